// Round 5
// baseline (586.663 us; speedup 1.0000x reference)
//
#include <hip/hip_runtime.h>
#include <stdint.h>

namespace {
constexpr int  kN  = 10000;
constexpr int  kE  = 320000;
constexpr long kPOff = 10000;                      // p offset (floats) in d_out
constexpr long kHOff = 10000L + 100000000L;        // h_new offset
constexpr long kTOff = kHOff + 320000L;            // t offset
}

typedef float f32x4 __attribute__((ext_vector_type(4)));

__device__ __forceinline__ float shfl32(float v, int k) { return __shfl(v, k, 32); }

// Per-node precompute: z = cat[x,h]@W_enc+b_enc ; zwd = z@W_msg[0:32]+b_msg ;
// zws = z@W_msg[32:64]. One node per half-wave, lane j = channel j.
// Also zeroes deg/cursor.
__global__ __launch_bounds__(256) void encz_kernel(
    const float* __restrict__ x, const float* __restrict__ h,
    const float* __restrict__ W_enc, const float* __restrict__ b_enc,
    const float* __restrict__ W_msg, const float* __restrict__ b_msg,
    float* __restrict__ z, float* __restrict__ zwd, float* __restrict__ zws,
    int* __restrict__ deg, int* __restrict__ cursor)
{
    int t = blockIdx.x * 256 + threadIdx.x;
    if (t < kN) { deg[t] = 0; cursor[t] = 0; }

    int lane = threadIdx.x & 63;
    int wid  = threadIdx.x >> 6;
    int half = lane >> 5;
    int j    = lane & 31;
    int i = blockIdx.x * 8 + wid * 2 + half;
    if (i >= kN) return;

    float hj = h[(long)i * 32 + j];
    float xi = x[i];
    float zj = fmaf(xi, W_enc[j], b_enc[j]);
#pragma unroll
    for (int k = 0; k < 32; ++k)
        zj = fmaf(shfl32(hj, k), W_enc[(1 + k) * 32 + j], zj);

    z[(long)i * 32 + j] = zj;

    float dv = b_msg[j], sv = 0.0f;
#pragma unroll
    for (int k = 0; k < 32; ++k) {
        float zk = shfl32(zj, k);
        dv = fmaf(zk, W_msg[k * 32 + j], dv);
        sv = fmaf(zk, W_msg[(32 + k) * 32 + j], sv);
    }
    zwd[(long)i * 32 + j] = dv;
    zws[(long)i * 32 + j] = sv;
}

__global__ __launch_bounds__(256) void hist_kernel(const int* __restrict__ dst,
                                                   int* __restrict__ deg)
{
    int e = blockIdx.x * 256 + threadIdx.x;
    if (e < kE) atomicAdd(&deg[dst[e]], 1);
}

// exclusive prefix sum of deg[10000] -> rowptr ; single block of 256 threads
__global__ __launch_bounds__(256) void scan_kernel(const int* __restrict__ deg,
                                                   int* __restrict__ rowptr)
{
    __shared__ int part[256];
    const int CH = 40;                  // 256*40 = 10240 >= kN
    int t = threadIdx.x;
    int vals[CH];
    int local = 0;
#pragma unroll
    for (int i = 0; i < CH; ++i) {
        int idx = t * CH + i;
        int v = (idx < kN) ? deg[idx] : 0;
        vals[i] = local;
        local += v;
    }
    part[t] = local;
    __syncthreads();
    for (int off = 1; off < 256; off <<= 1) {
        int v = (t >= off) ? part[t - off] : 0;
        __syncthreads();
        part[t] += v;
        __syncthreads();
    }
    int excl = part[t] - local;
#pragma unroll
    for (int i = 0; i < CH; ++i) {
        int idx = t * CH + i;
        if (idx < kN) rowptr[idx] = excl + vals[i];
    }
}

__global__ __launch_bounds__(256) void scatter_kernel(
    const int* __restrict__ dst, const int* __restrict__ rowptr,
    int* __restrict__ cursor, int* __restrict__ elist)
{
    int e = blockIdx.x * 256 + threadIdx.x;
    if (e >= kE) return;
    int d = dst[e];
    int pos = atomicAdd(&cursor[d], 1);
    elist[rowptr[d] + pos] = e;
}

// One dest per half-wave, lane j = channel j. No atomics, no per-edge GEMV:
// msg_j = zwd[d][j] + zws[s][j] + w_e*Ww_j ; m[d][j] = max (-inf -> 0).
__global__ __launch_bounds__(256) void gathermax_kernel(
    const int* __restrict__ src, const float* __restrict__ w,
    const float* __restrict__ zwd, const float* __restrict__ zws,
    const int* __restrict__ rowptr, const int* __restrict__ deg,
    const int* __restrict__ elist, const float* __restrict__ W_msg,
    float* __restrict__ m)
{
    int lane = threadIdx.x & 63;
    int wid  = threadIdx.x >> 6;
    int half = lane >> 5;
    int j    = lane & 31;
    int d = blockIdx.x * 8 + wid * 2 + half;
    if (d >= kN) return;

    float Ww = W_msg[64 * 32 + j];
    float partial = zwd[(long)d * 32 + j];
    float mx = -__builtin_inff();
    int base = rowptr[d], cnt = deg[d];

    if (cnt > 0) {
        // software-pipelined: prefetch next edge's scalars during current zws read
        int e = elist[base];
        int s = src[e];
        float we = w[e];
        for (int i = 1; i < cnt; ++i) {
            int e2 = elist[base + i];
            int s2 = src[e2];
            float we2 = w[e2];
            float msg = fmaf(we, Ww, partial + zws[(long)s * 32 + j]);
            mx = fmaxf(mx, msg);
            s = s2; we = we2;
        }
        float msg = fmaf(we, Ww, partial + zws[(long)s * 32 + j]);
        mx = fmaxf(mx, msg);
    }
    m[(long)d * 32 + j] = (mx == -__builtin_inff()) ? 0.0f : mx;
}

// h_new = cat[z,m0]@W_upd+b_upd ; y = cat[z,h_new]@W_dec+b_dec ;
// a[i] = h_new·W_pred[0:32] ; b[i] = h_new·W_pred[32:64] ; per-wave h_new partials.
__global__ __launch_bounds__(256) void updn_kernel(
    const float* __restrict__ z, const float* __restrict__ m,
    const float* __restrict__ W_upd, const float* __restrict__ b_upd,
    const float* __restrict__ W_dec, const float* __restrict__ b_dec,
    const float* __restrict__ W_pred,
    float* __restrict__ y_out, float* __restrict__ h_out,
    float* __restrict__ a_out, float* __restrict__ b_out,
    float* __restrict__ partials)
{
    int i = blockIdx.x * 256 + threadIdx.x;
    bool valid = i < kN;
    int ii = valid ? i : (kN - 1);

    float acc[32];
#pragma unroll
    for (int jj = 0; jj < 32; ++jj) acc[jj] = b_upd[jj];
    float yv = b_dec[0];

    const float4* z4 = reinterpret_cast<const float4*>(z + (long)ii * 32);
#pragma unroll
    for (int q = 0; q < 8; ++q) {
        float4 v = z4[q];
        float in0 = v.x, in1 = v.y, in2 = v.z, in3 = v.w;
        int k = q * 4;
        yv = fmaf(in0, W_dec[k + 0], yv);
        yv = fmaf(in1, W_dec[k + 1], yv);
        yv = fmaf(in2, W_dec[k + 2], yv);
        yv = fmaf(in3, W_dec[k + 3], yv);
        const float* W0 = W_upd + (k + 0) * 32;
        const float* W1 = W_upd + (k + 1) * 32;
        const float* W2 = W_upd + (k + 2) * 32;
        const float* W3 = W_upd + (k + 3) * 32;
#pragma unroll
        for (int jj = 0; jj < 32; ++jj) acc[jj] = fmaf(in0, W0[jj], acc[jj]);
#pragma unroll
        for (int jj = 0; jj < 32; ++jj) acc[jj] = fmaf(in1, W1[jj], acc[jj]);
#pragma unroll
        for (int jj = 0; jj < 32; ++jj) acc[jj] = fmaf(in2, W2[jj], acc[jj]);
#pragma unroll
        for (int jj = 0; jj < 32; ++jj) acc[jj] = fmaf(in3, W3[jj], acc[jj]);
    }

    const float NEG_INF = -__builtin_inff();
    const float4* m4 = reinterpret_cast<const float4*>(m + (long)ii * 32);
#pragma unroll
    for (int q = 0; q < 8; ++q) {
        float4 v = m4[q];
        float in0 = (v.x == NEG_INF) ? 0.0f : v.x;
        float in1 = (v.y == NEG_INF) ? 0.0f : v.y;
        float in2 = (v.z == NEG_INF) ? 0.0f : v.z;
        float in3 = (v.w == NEG_INF) ? 0.0f : v.w;
        int k = 32 + q * 4;
        const float* W0 = W_upd + (k + 0) * 32;
        const float* W1 = W_upd + (k + 1) * 32;
        const float* W2 = W_upd + (k + 2) * 32;
        const float* W3 = W_upd + (k + 3) * 32;
#pragma unroll
        for (int jj = 0; jj < 32; ++jj) acc[jj] = fmaf(in0, W0[jj], acc[jj]);
#pragma unroll
        for (int jj = 0; jj < 32; ++jj) acc[jj] = fmaf(in1, W1[jj], acc[jj]);
#pragma unroll
        for (int jj = 0; jj < 32; ++jj) acc[jj] = fmaf(in2, W2[jj], acc[jj]);
#pragma unroll
        for (int jj = 0; jj < 32; ++jj) acc[jj] = fmaf(in3, W3[jj], acc[jj]);
    }

    float av = 0.0f, bv = 0.0f;
#pragma unroll
    for (int k = 0; k < 32; ++k) {
        yv = fmaf(acc[k], W_dec[32 + k], yv);
        av = fmaf(acc[k], W_pred[k], av);
        bv = fmaf(acc[k], W_pred[32 + k], bv);
    }

    if (valid) {
        y_out[i] = yv;
        a_out[i] = av;
        b_out[i] = bv;
        float4* hrow = reinterpret_cast<float4*>(h_out + (long)i * 32);
#pragma unroll
        for (int q = 0; q < 8; ++q)
            hrow[q] = make_float4(acc[q * 4 + 0], acc[q * 4 + 1], acc[q * 4 + 2], acc[q * 4 + 3]);
    }

    // per-wave partial sums of h_new -> global (no atomics)
    int wslot = blockIdx.x * 4 + ((threadIdx.x >> 6) & 3);
#pragma unroll
    for (int jj = 0; jj < 32; ++jj) {
        float v = valid ? acc[jj] : 0.0f;
#pragma unroll
        for (int off = 32; off; off >>= 1) v += __shfl_down(v, off, 64);
        if ((threadIdx.x & 63) == 0) partials[(long)wslot * 32 + jj] = v;
    }
}

// t = (mean(h_new) @ W_term + b_term) ; one wave reduces 160x32 partials
__global__ void term_kernel(const float* __restrict__ partials,
                            const float* __restrict__ W_term,
                            const float* __restrict__ b_term,
                            float* __restrict__ t_out)
{
    int l = threadIdx.x;
    float s = 0.0f;
    if (l < 32) {
        for (int r = 0; r < 160; ++r) s += partials[(long)r * 32 + l];
        s = (s * (1.0f / (float)kN)) * W_term[l];
    }
#pragma unroll
    for (int off = 32; off; off >>= 1) s += __shfl_down(s, off, 64);
    if (l == 0) t_out[0] = s + b_term[0];
}

__global__ __launch_bounds__(256) void fill_kernel(float* __restrict__ p)
{
    long idx = (long)blockIdx.x * 256 + threadIdx.x;
    long stride = (long)gridDim.x * 256;
    const long total4 = (long)kN * (long)kN / 4;   // 25,000,000
    f32x4 v = { -1e9f, -1e9f, -1e9f, -1e9f };
    f32x4* p4 = reinterpret_cast<f32x4*>(p);
    for (long i = idx; i < total4; i += stride)
        p4[i] = v;
}

// p[d,s] = a[d] + b[s] + w_e*W_pred[64] + b_pred
__global__ __launch_bounds__(256) void predl_kernel(
    const int* __restrict__ src, const int* __restrict__ dst,
    const float* __restrict__ w, const float* __restrict__ a,
    const float* __restrict__ b, const float* __restrict__ W_pred,
    const float* __restrict__ b_pred, float* __restrict__ p)
{
    int e = blockIdx.x * 256 + threadIdx.x;
    if (e >= kE) return;
    int d = dst[e], s = src[e];
    float score = a[d] + b[s] + fmaf(w[e], W_pred[64], b_pred[0]);
    p[(long)d * kN + s] = score;
}

extern "C" void kernel_launch(void* const* d_in, const int* in_sizes, int n_in,
                              void* d_out, int out_size, void* d_ws, size_t ws_size,
                              hipStream_t stream)
{
    const int*   sources = (const int*)d_in[0];
    const int*   dests   = (const int*)d_in[1];
    const float* weights = (const float*)d_in[2];
    const float* x       = (const float*)d_in[3];
    const float* h       = (const float*)d_in[4];
    const float* W_enc   = (const float*)d_in[5];
    const float* b_enc   = (const float*)d_in[6];
    const float* W_msg   = (const float*)d_in[7];
    const float* b_msg   = (const float*)d_in[8];
    const float* W_upd   = (const float*)d_in[9];
    const float* b_upd   = (const float*)d_in[10];
    const float* W_dec   = (const float*)d_in[11];
    const float* b_dec   = (const float*)d_in[12];
    const float* W_term  = (const float*)d_in[13];
    const float* b_term  = (const float*)d_in[14];
    const float* W_pred  = (const float*)d_in[15];
    const float* b_pred  = (const float*)d_in[16];

    float* out   = (float*)d_out;
    float* y_out = out;
    float* p_out = out + kPOff;
    float* h_out = out + kHOff;
    float* t_out = out + kTOff;

    // workspace layout (f32 unless noted)
    float* z        = (float*)d_ws;                  // N*32
    float* m        = z   + (long)kN * 32;           // N*32
    float* zwd      = m   + (long)kN * 32;           // N*32
    float* zws      = zwd + (long)kN * 32;           // N*32
    float* a_ws     = zws + (long)kN * 32;           // N
    float* b_ws     = a_ws + kN;                     // N
    float* partials = b_ws + kN;                     // 160*32
    int*   deg      = (int*)(partials + 160 * 32);   // N i32
    int*   rowptr   = deg + kN;                      // N i32
    int*   cursor   = rowptr + kN;                   // N i32
    // edge list borrows the p output region (fill runs AFTER gathermax)
    int*   elist    = (int*)p_out;                   // E i32

    encz_kernel<<<(kN + 7) / 8, 256, 0, stream>>>(x, h, W_enc, b_enc, W_msg, b_msg,
                                                  z, zwd, zws, deg, cursor);
    hist_kernel<<<(kE + 255) / 256, 256, 0, stream>>>(dests, deg);
    scan_kernel<<<1, 256, 0, stream>>>(deg, rowptr);
    scatter_kernel<<<(kE + 255) / 256, 256, 0, stream>>>(dests, rowptr, cursor, elist);
    gathermax_kernel<<<(kN + 7) / 8, 256, 0, stream>>>(sources, weights, zwd, zws,
                                                       rowptr, deg, elist, W_msg, m);
    updn_kernel<<<(kN + 255) / 256, 256, 0, stream>>>(z, m, W_upd, b_upd, W_dec, b_dec,
                                                      W_pred, y_out, h_out, a_ws, b_ws,
                                                      partials);
    term_kernel<<<1, 64, 0, stream>>>(partials, W_term, b_term, t_out);
    fill_kernel<<<8192, 256, 0, stream>>>(p_out);
    predl_kernel<<<(kE + 255) / 256, 256, 0, stream>>>(sources, dests, weights, a_ws, b_ws,
                                                       W_pred, b_pred, p_out);
}